// Round 21
// baseline (158.827 us; speedup 1.0000x reference)
//
#include <hip/hip_runtime.h>

// VectorQuantizer: z [8,64,64,64] fp32 (BCHW), embedding [8192,64] fp32.
// Outputs (concat): z_q [8,64,64,64] fp32 (BCHW), indices [32768] as fp32.
//
// R34: NSTAGE 128 -> 256 (32KB stages, 8 epochs) in the 16-wave k_mfma.
// R33 post-mortem: KSPLIT=4 grid is only 4096 waves = 16 waves/CU one-shot;
// residency is mined out (R31==R33 at ~66-67us). Pipe sums (VALU ~10,
// ds_read ~5, MFMA ~4, HBM ~1.3us) << 66us -> the cost is the 16 per-stage
// barrier+vmcnt-drain convoys. Halve them: 256-code stages (esw combo
// layout is linear in code order, so sub 0..15 / base=sub*1024 / stride
// 32KB generalize with no layout change). sid=(nb<<4)|sub still 7 bits.
// LDS 2x32KB=64KB/block; grid 256 blocks = 1 block/CU (unchanged).
// Tier structure (R31/R33-proven): KSPLIT=4, 7-bit mantissa id,
// b2-completeness shortlist in k_merge, suspect-split 4x512-code chunks.
// Staging (R12): global_load_lds 16B registerless from pre-swizzled codebook.

#define NPIX 32768
#define NE   8192
#define EDIM 64
#define HW   4096
#define NSTAGE 256          // codes per LDS stage (16 subtiles of 16)
#define KSPLIT 4
#define CPS  (NE / KSPLIT)  // 2048 codes per split
#define NSTG (CPS / NSTAGE) // 8 stages per block
#define MARGIN1 6.0e-4f
#define NSET 2              // row-sets of 16 pixels per wave (PPW=32)

typedef _Float16 f16x8 __attribute__((ext_vector_type(8)));
typedef float f32x4  __attribute__((ext_vector_type(4)));

__device__ __forceinline__ short f2h_bits(float x) {
    _Float16 h = (_Float16)x;
    short s; __builtin_memcpy(&s, &h, 2); return s;
}
// map float to unsigned with same total order
__device__ __forceinline__ unsigned int order_u32(float f) {
    unsigned int s = __float_as_uint(f);
    return (s & 0x80000000u) ? ~s : (s | 0x80000000u);
}
// async global->LDS, 16B/lane; HW writes lane i at lds_base + i*16 (wave-uniform base)
__device__ __forceinline__ void gload_lds16(const void* g, void* l) {
    __builtin_amdgcn_global_load_lds(
        (const __attribute__((address_space(1))) void*)g,
        (__attribute__((address_space(3))) void*)l, 16, 0, 0);
}

// ---------------- prep (fused): codebook (swizzled fp16) + pixels ------------
// esw layout: per 64-code group, 8 combos (sub[4] x {k0,k1}) x 1KB; within
// combo, MFMA-B fragment order: slot frag_lane=(o&3)*16+code_col holds 8
// channels (16B). Combos are linear in code order -> any stage size works.
__global__ __launch_bounds__(256) void k_prep(const float* __restrict__ emb,
                                              const float* __restrict__ z,
                                              float* __restrict__ e_norm,
                                              float* __restrict__ se_half,
                                              short* __restrict__ esw,
                                              float* __restrict__ zn,
                                              unsigned* __restrict__ counter) {
    if (blockIdx.x == 0 && threadIdx.x == 0) counter[0] = 0u;
    if (blockIdx.x < NE / 4) {
        // --- codebook: 1 code per wave, lane = channel ---
        const int wave = threadIdx.x >> 6;
        const int lane = threadIdx.x & 63;
        const int n = blockIdx.x * 4 + wave;
        float v = emb[n * EDIM + lane];
        float ss = v * v;
        #pragma unroll
        for (int off = 32; off; off >>= 1) ss += __shfl_xor(ss, off, 64);
        const float inv = 1.0f / fmaxf(sqrtf(ss), 1e-12f);
        const float en = v * inv;
        e_norm[n * EDIM + lane] = en;
        // swizzled fp16 write (c = lane)
        const int grp = n >> 6, cs = n & 63;
        const int sub = cs >> 4, colb = cs & 15;
        const int o = lane >> 3, j = lane & 7;     // o: khalf=o>>2, quad=o&3
        const int slot = ((o & 3) * 16 + colb) * 8 + j;
        esw[grp * 4096 + (sub * 2 + (o >> 2)) * 512 + slot] = f2h_bits(en);
        float s2 = en * en;
        #pragma unroll
        for (int off = 32; off; off >>= 1) s2 += __shfl_xor(s2, off, 64);
        if (lane == 0) se_half[n] = 0.5f * s2;
    } else {
        // --- pixels: single-pass normalize -> zn fp32 row-major [p][c] ---
        const int p = (blockIdx.x - NE / 4) * 256 + threadIdx.x;
        const int b = p >> 12, hw = p & (HW - 1);
        const float* zp = z + b * (EDIM * HW) + hw;
        float v[EDIM];
        #pragma unroll
        for (int c = 0; c < EDIM; ++c) v[c] = zp[c * HW];
        float ss = 0.0f;
        #pragma unroll
        for (int c = 0; c < EDIM; ++c) ss = fmaf(v[c], v[c], ss);
        const float inv = 1.0f / fmaxf(sqrtf(ss), 1e-12f);
        #pragma unroll
        for (int c4 = 0; c4 < 16; ++c4) {
            float4 o;
            o.x = v[c4 * 4 + 0] * inv;
            o.y = v[c4 * 4 + 1] * inv;
            o.z = v[c4 * 4 + 2] * inv;
            o.w = v[c4 * 4 + 3] * inv;
            *(float4*)(zn + p * EDIM + c4 * 4) = o;
        }
    }
}

// ---------------- tier-1 k_mfma: split-K partial top-2, 16-wave blocks ------
// Block: 16 waves x 32 pixels = 512 pixels, one codebook quarter (blockIdx.y).
// v = dot + 2 in [1,3]; argmin dist == argmax v (unit vectors). Low 7 mantissa
// bits carry the candidate id (stage*16+sub, 8 stages). Layouts (HW-verified):
// A[m=lane&15][k=quad*8+j], B[k=quad*8+j][n=lane&15], C/D row=(lane>>4)*4+reg,
// col=lane&15.
__global__ __launch_bounds__(1024, 1) void k_mfma(const float* __restrict__ zn,
                                                  const short* __restrict__ esw,
                                                  float2* __restrict__ pv,   // [g][p] {b1,b2} (max-space)
                                                  unsigned* __restrict__ pi) // [g][p] i1
{
    __shared__ __align__(16) short es[2][NSTAGE * EDIM];   // 2 x 32KB

    const int tid  = threadIdx.x;             // 0..1023
    const int wave = tid >> 6, lane = tid & 63;
    const int quad = lane >> 4, col = lane & 15;
    const int p0   = blockIdx.x * 512 + wave * 32;  // wave's 32 pixels (2 sets)
    const int g    = blockIdx.y;                    // codebook quarter
    const int kbase = g * CPS;

    // A fragments: 2 sets of 16 pixels; fp32 zn -> fp16 (single product)
    f16x8 ah[NSET][2];
    #pragma unroll
    for (int s = 0; s < NSET; ++s) {
        const float* zr = zn + (p0 + s * 16 + col) * EDIM;
        #pragma unroll
        for (int kc = 0; kc < 2; ++kc) {
            float f[8];
            *(float4*)(f + 0) = *(const float4*)(zr + kc * 32 + quad * 8 + 0);
            *(float4*)(f + 4) = *(const float4*)(zr + kc * 32 + quad * 8 + 4);
            #pragma unroll
            for (int i = 0; i < 8; ++i) ah[s][kc][i] = (_Float16)f[i];
        }
    }

    // top-2 state in max-space; values stuffed with 7-bit id; b1 >= b2 invariant
    float b1[NSET][4], b2[NSET][4];
    #pragma unroll
    for (int s = 0; s < NSET; ++s)
        #pragma unroll
        for (int r = 0; r < 4; ++r) { b1[s][r] = 0.0f; b2[s][r] = 0.0f; }

    const f32x4 cini = {2.0f, 2.0f, 2.0f, 2.0f};   // |z|=|e|=1 -> bias constant

    // staging: 32 combos x 1KB per 32KB stage, 2 combos per wave (16 waves)
    const int combo0 = wave * 2;
    const char* gsrc0 = (const char*)esw + (size_t)kbase * 128
                        + combo0 * 1024 + lane * 16;
    // prologue: issue stage 0 -> buf 0
    #pragma unroll
    for (int it = 0; it < 2; ++it)
        gload_lds16(gsrc0 + it * 1024, (char*)&es[0][0] + (combo0 + it) * 1024);

    for (int nb = 0; nb < NSTG; ++nb) {
        const int cur = nb & 1;
        __syncthreads();   // vmcnt drained: buf[cur] complete; buf[cur^1] reusable
        if (nb + 1 < NSTG) {
            const char* gsrc = gsrc0 + (size_t)(nb + 1) * (NSTAGE * EDIM * 2);
            #pragma unroll
            for (int it = 0; it < 2; ++it)
                gload_lds16(gsrc + it * 1024,
                            (char*)&es[cur ^ 1][0] + (combo0 + it) * 1024);
        }

        const short* esb = es[cur];
        #pragma unroll
        for (int sub = 0; sub < 16; ++sub) {      // 16 subtiles of 16 codes
            const short* base = esb + sub * 1024;
            const f16x8 bh0 = *(const f16x8*)(base + lane * 8);
            const f16x8 bh1 = *(const f16x8*)(base + 512 + lane * 8);
            const unsigned sid = (unsigned)((nb << 4) | sub);  // 7-bit id, uniform
            #pragma unroll
            for (int s = 0; s < NSET; ++s) {
                // 2-deep chain seeded with C = {2.0}
                f32x4 acc;
                acc = __builtin_amdgcn_mfma_f32_16x16x32_f16(ah[s][0], bh0, cini, 0, 0, 0);
                acc = __builtin_amdgcn_mfma_f32_16x16x32_f16(ah[s][1], bh1, acc, 0, 0, 0);
                #pragma unroll
                for (int r = 0; r < 4; ++r) {
                    // stuff candidate id into low mantissa bits (v_and_or_b32)
                    const float v = __uint_as_float(
                        (__float_as_uint(acc[r]) & 0xFFFFFF80u) | sid);
                    // b1>=b2 invariant -> med3 == new 2nd-max; then running max
                    b2[s][r] = __builtin_amdgcn_fmed3f(v, b2[s][r], b1[s][r]);
                    b1[s][r] = fmaxf(b1[s][r], v);
                }
            }
        }
    }

    // recover winning index from b1's stuffed id (col is lane-implicit)
    int i1[NSET][4];
    #pragma unroll
    for (int s = 0; s < NSET; ++s)
        #pragma unroll
        for (int r = 0; r < 4; ++r) {
            const unsigned id7 = __float_as_uint(b1[s][r]) & 127u;
            i1[s][r] = kbase + (int)(id7 << 4) + col;
        }

    // merge top-2 across the 16 col-lanes (xor 1,2,4,8 stays inside quad group)
    #pragma unroll
    for (int m = 1; m <= 8; m <<= 1) {
        #pragma unroll
        for (int s = 0; s < NSET; ++s)
            #pragma unroll
            for (int r = 0; r < 4; ++r) {
                const float ob1 = __shfl_xor(b1[s][r], m, 64);
                const int   oi1 = __shfl_xor(i1[s][r], m, 64);
                const float ob2 = __shfl_xor(b2[s][r], m, 64);
                const bool take = (ob1 > b1[s][r]) || (ob1 == b1[s][r] && oi1 < i1[s][r]);
                b2[s][r] = fmaxf(fmaxf(b2[s][r], ob2), fminf(b1[s][r], ob1));
                b1[s][r] = take ? ob1 : b1[s][r];
                i1[s][r] = take ? oi1 : i1[s][r];
            }
    }
    if (col == 0) {
        #pragma unroll
        for (int s = 0; s < NSET; ++s)
            #pragma unroll
            for (int r = 0; r < 4; ++r) {
                const int p = p0 + s * 16 + quad * 4 + r;   // C/D row = quad*4 + r
                pv[g * NPIX + p] = make_float2(b1[s][r], b2[s][r]);
                pi[g * NPIX + p] = (unsigned)i1[s][r];
            }
    }
}

// ---------------- merge: combine splits; rescore shortlist; enqueue suspects -
// thr = gb1 - MARGIN1. gb2 < thr -> unflagged fast path (gi1). Else: exact
// fp32 rescore of the shortlist {i1[g] : b1[g] >= thr}. If no split's
// b2 >= thr the shortlist is complete -> final. Else seed packed[p] with the
// shortlist key and enqueue 4 (pixel, 512-chunk) entries per suspect split
// (b2 >= thr); k_recheck atomicMins the exact scan of those chunks.
__global__ __launch_bounds__(256) void k_merge(const float2* __restrict__ pv,
                                               const unsigned* __restrict__ pi,
                                               const float* __restrict__ zn,
                                               const float* __restrict__ e_norm,
                                               const float* __restrict__ se_half,
                                               unsigned* __restrict__ idx_arr,
                                               unsigned* __restrict__ list2,
                                               unsigned* __restrict__ counter,
                                               unsigned long long* __restrict__ packed) {
    const int p = blockIdx.x * 256 + threadIdx.x;
    float2 v[KSPLIT]; unsigned ix[KSPLIT];
    #pragma unroll
    for (int gg = 0; gg < KSPLIT; ++gg) {
        v[gg] = pv[gg * NPIX + p];
        ix[gg] = pi[gg * NPIX + p];
    }
    // global noisy top-1 (ascending g + strict > == first-occurrence)
    float gb1 = v[0].x; unsigned gi1 = ix[0]; int win = 0;
    #pragma unroll
    for (int gg = 1; gg < KSPLIT; ++gg)
        if (v[gg].x > gb1) { gb1 = v[gg].x; gi1 = ix[gg]; win = gg; }
    float gb2 = -3.0e38f;
    #pragma unroll
    for (int gg = 0; gg < KSPLIT; ++gg) {
        gb2 = fmaxf(gb2, v[gg].y);
        if (gg != win) gb2 = fmaxf(gb2, v[gg].x);
    }
    const float thr = gb1 - MARGIN1;
    if (gb2 < thr) {                      // clear winner
        idx_arr[p] = gi1;
        return;
    }
    // exact fp32 rescore of the shortlist {i1[g] : b1[g] >= thr}
    float zr[EDIM];
    #pragma unroll
    for (int c4 = 0; c4 < 16; ++c4)
        *(float4*)(zr + c4 * 4) = *(const float4*)(zn + (size_t)p * EDIM + c4 * 4);
    float best = 3.0e38f; int bidx = 0x7FFFFFFF;
    #pragma unroll
    for (int gg = 0; gg < KSPLIT; ++gg) {
        if (v[gg].x >= thr) {
            const int c = (int)ix[gg];
            const float* er = e_norm + (size_t)c * EDIM;
            float s = 0.0f;
            #pragma unroll
            for (int k = 0; k < EDIM; ++k) s = fmaf(zr[k], er[k], s);
            const float d = se_half[c] - s;
            if (d < best || (d == best && c < bidx)) { best = d; bidx = c; }
        }
    }
    bool esc = false;
    #pragma unroll
    for (int gg = 0; gg < KSPLIT; ++gg) esc |= (v[gg].y >= thr);
    if (!esc) {                           // shortlist provably complete
        idx_arr[p] = (unsigned)bidx;
        return;
    }
    // escalate: seed with shortlist key; scan only suspect splits' chunks
    packed[p] = ((unsigned long long)order_u32(best) << 32) | (unsigned)bidx;
    idx_arr[p] = 0x80000000u | (unsigned)bidx;
    #pragma unroll
    for (int gg = 0; gg < KSPLIT; ++gg) {
        if (v[gg].y >= thr) {
            const unsigned pos = atomicAdd(&counter[0], 4u);
            if (pos + 3 < 2 * NPIX) {
                list2[pos]     = (unsigned)p | ((unsigned)(gg * 4)     << 16);
                list2[pos + 1] = (unsigned)p | ((unsigned)(gg * 4 + 1) << 16);
                list2[pos + 2] = (unsigned)p | ((unsigned)(gg * 4 + 2) << 16);
                list2[pos + 3] = (unsigned)p | ((unsigned)(gg * 4 + 3) << 16);
            }
        }
    }
}

// ---------------- tier-3: exact fp32 scan of suspect (pixel, chunk) items ----
// entry = p | (chunk << 16); chunk = 512-code block. Coalesced: 4 codes x 16
// lanes per b128 (contiguous 1KB from L2-resident e_norm); 4 independent
// shfl-reduce chains. One wave per entry, grid-strided.
__global__ __launch_bounds__(256) void k_recheck(const float* __restrict__ zn,
                                                 const float* __restrict__ e_norm,
                                                 const float* __restrict__ se_half,
                                                 const unsigned* __restrict__ list2,
                                                 const unsigned* __restrict__ counter,
                                                 unsigned long long* __restrict__ packed) {
    const int lane  = threadIdx.x & 63;
    const int k     = lane >> 4;        // code-in-group 0..3
    const int m     = lane & 15;        // c4 index 0..15
    const int wglob = (blockIdx.x * 256 + threadIdx.x) >> 6;
    const int nwav  = (gridDim.x * 256) >> 6;
    int cnt = (int)counter[0]; if (cnt > 2 * NPIX) cnt = 2 * NPIX;
    const float4* e4 = (const float4*)e_norm;

    for (int item = wglob; item < cnt; item += nwav) {
        const unsigned e = list2[item];
        const int p     = (int)(e & 0xFFFFu);
        const int chunk = (int)(e >> 16);
        const float4 zv = *(const float4*)(zn + (size_t)p * EDIM + m * 4);
        float best = 3.0e38f; int bidx = 0;
        for (int t4 = 0; t4 < 32; ++t4) {              // 16 codes per iteration
            float s[4]; int n[4];
            #pragma unroll
            for (int j = 0; j < 4; ++j) {
                n[j] = chunk * 512 + (t4 * 4 + j) * 4 + k;
                const float4 ev = e4[n[j] * 16 + m];   // lane-linear: 1KB contiguous
                s[j] = fmaf(zv.w, ev.w, fmaf(zv.z, ev.z,
                       fmaf(zv.y, ev.y, zv.x * ev.x)));
            }
            #pragma unroll
            for (int j = 0; j < 4; ++j) s[j] += __shfl_xor(s[j], 1, 64);
            #pragma unroll
            for (int j = 0; j < 4; ++j) s[j] += __shfl_xor(s[j], 2, 64);
            #pragma unroll
            for (int j = 0; j < 4; ++j) s[j] += __shfl_xor(s[j], 4, 64);
            #pragma unroll
            for (int j = 0; j < 4; ++j) s[j] += __shfl_xor(s[j], 8, 64);
            #pragma unroll
            for (int j = 0; j < 4; ++j) {              // codes ascend over (t4,j)
                const float d = se_half[n[j]] - s[j];
                if (d < best) { best = d; bidx = n[j]; }
            }
        }
        #pragma unroll
        for (int mm = 1; mm <= 32; mm <<= 1) {         // wave first-min
            const float ob = __shfl_xor(best, mm, 64);
            const int   oi = __shfl_xor(bidx, mm, 64);
            if (ob < best || (ob == best && oi < bidx)) { best = ob; bidx = oi; }
        }
        if (lane == 0) {
            const unsigned long long key =
                ((unsigned long long)order_u32(best) << 32) | (unsigned)bidx;
            atomicMin(&packed[p], key);
        }
    }
}

// ---------------- finalize: write indices + gather z_q (4 thr/pixel) ---------
__global__ __launch_bounds__(256) void k_finalize(const unsigned* __restrict__ idx_arr,
                                                  const unsigned long long* __restrict__ packed,
                                                  const float* __restrict__ e_norm,
                                                  float* __restrict__ out) {
    const int pl = threadIdx.x & 63;
    const int q  = threadIdx.x >> 6;                  // channel quarter 0..3
    const int p  = blockIdx.x * 64 + pl;
    const unsigned v = idx_arr[p];
    const int bidx = (v & 0x80000000u) ? (int)(packed[p] & 0xFFFFFFFFull)
                                       : (int)v;
    if (q == 0) out[NPIX * EDIM + p] = (float)bidx;
    const int b = p >> 12, hw = p & (HW - 1);
    float* op = out + b * (EDIM * HW) + hw;
    const float4* ep4 = (const float4*)(e_norm + (size_t)bidx * EDIM + q * 16);
    #pragma unroll
    for (int j = 0; j < 4; ++j) {
        const float4 e = ep4[j];
        const int c = q * 16 + j * 4;
        op[(c + 0) * HW] = e.x; op[(c + 1) * HW] = e.y;   // coalesced per c
        op[(c + 2) * HW] = e.z; op[(c + 3) * HW] = e.w;
    }
}

extern "C" void kernel_launch(void* const* d_in, const int* in_sizes, int n_in,
                              void* d_out, int out_size, void* d_ws, size_t ws_size,
                              hipStream_t stream) {
    const float* z   = (const float*)d_in[0];
    const float* emb = (const float*)d_in[1];
    float* out = (float*)d_out;

    // workspace layout (~13.8 MB)
    float* e_norm  = (float*)d_ws;                       // 2 MB
    float* se_half = e_norm + NE * EDIM;                 // 32 KB
    short* esw = (short*)(se_half + NE);                 // 1 MB (swizzled fp16)
    float* zn = (float*)(esw + NE * EDIM);               // 8 MB
    unsigned* idx_arr = (unsigned*)(zn + NPIX * EDIM);   // 128 KB
    unsigned* list2   = idx_arr + NPIX;                  // 256 KB (suspect items)
    unsigned* counter = list2 + 2 * NPIX;                // 4 B (+pad)
    unsigned long long* packed = (unsigned long long*)(counter + 64); // 256 KB
    float2*   pv = (float2*)(packed + NPIX);             // 1 MB
    unsigned* pi = (unsigned*)(pv + KSPLIT * NPIX);      // 512 KB

    k_prep<<<NE / 4 + NPIX / 256, 256, 0, stream>>>(emb, z, e_norm, se_half,
                                                    esw, zn, counter);
    k_mfma<<<dim3(NPIX / 512, KSPLIT), 1024, 0, stream>>>(zn, esw, pv, pi);
    k_merge<<<NPIX / 256, 256, 0, stream>>>(pv, pi, zn, e_norm, se_half,
                                            idx_arr, list2, counter, packed);
    k_recheck<<<1024, 256, 0, stream>>>(zn, e_norm, se_half, list2, counter, packed);
    k_finalize<<<NPIX / 64, 256, 0, stream>>>(idx_arr, packed, e_norm, out);
}

// Round 22
// 155.579 us; speedup vs baseline: 1.0209x; 1.0209x over previous
//
#include <hip/hip_runtime.h>

// VectorQuantizer: z [8,64,64,64] fp32 (BCHW), embedding [8192,64] fp32.
// Outputs (concat): z_q [8,64,64,64] fp32 (BCHW), indices [32768] as fp32.
//
// R35: revert to R33 (best measured: 156.8us). R34's NSTAGE=256 regressed
// k_mfma 66 -> 71.7us, falsifying the drain-count theory: at 16 one-shot
// waves/CU the kernel is intra-epoch latency-bound and NSTAGE=128 is the
// bracketed optimum. All axes probed: scoring precision (fp16 1-product +
// tiered exact refinement), selection (mantissa-id med3/max), schedule
// (2-phase __syncthreads; counted-vmcnt & barrier-free lose), fusion (3x
// lose), KSPLIT (4), block shape (1024-thr/16-wave), PPW (32), stage (128).
// Config: 16-wave k_mfma blocks, 2 blocks/CU (threads-capped), KSPLIT=4,
// 7-bit mantissa id, b2-completeness shortlist in k_merge, suspect-split
// 4x512-code chunk scans in k_recheck, 4-thr/pixel finalize gather.
// Staging (R12): global_load_lds 16B registerless from pre-swizzled codebook.

#define NPIX 32768
#define NE   8192
#define EDIM 64
#define HW   4096
#define NSTAGE 128          // codes per LDS stage (8 subtiles of 16)
#define KSPLIT 4
#define CPS  (NE / KSPLIT)  // 2048 codes per split
#define NSTG (CPS / NSTAGE) // 16 stages per block
#define MARGIN1 6.0e-4f
#define NSET 2              // row-sets of 16 pixels per wave (PPW=32)

typedef _Float16 f16x8 __attribute__((ext_vector_type(8)));
typedef float f32x4  __attribute__((ext_vector_type(4)));

__device__ __forceinline__ short f2h_bits(float x) {
    _Float16 h = (_Float16)x;
    short s; __builtin_memcpy(&s, &h, 2); return s;
}
// map float to unsigned with same total order
__device__ __forceinline__ unsigned int order_u32(float f) {
    unsigned int s = __float_as_uint(f);
    return (s & 0x80000000u) ? ~s : (s | 0x80000000u);
}
// async global->LDS, 16B/lane; HW writes lane i at lds_base + i*16 (wave-uniform base)
__device__ __forceinline__ void gload_lds16(const void* g, void* l) {
    __builtin_amdgcn_global_load_lds(
        (const __attribute__((address_space(1))) void*)g,
        (__attribute__((address_space(3))) void*)l, 16, 0, 0);
}

// ---------------- prep (fused): codebook (swizzled fp16) + pixels ------------
// esw layout: per 64-code group, 8 combos (sub[4] x {k0,k1}) x 1KB; within
// combo, MFMA-B fragment order: slot frag_lane=(o&3)*16+code_col holds 8
// channels (16B). A 128-code stage = two consecutive groups (16KB).
__global__ __launch_bounds__(256) void k_prep(const float* __restrict__ emb,
                                              const float* __restrict__ z,
                                              float* __restrict__ e_norm,
                                              float* __restrict__ se_half,
                                              short* __restrict__ esw,
                                              float* __restrict__ zn,
                                              unsigned* __restrict__ counter) {
    if (blockIdx.x == 0 && threadIdx.x == 0) counter[0] = 0u;
    if (blockIdx.x < NE / 4) {
        // --- codebook: 1 code per wave, lane = channel ---
        const int wave = threadIdx.x >> 6;
        const int lane = threadIdx.x & 63;
        const int n = blockIdx.x * 4 + wave;
        float v = emb[n * EDIM + lane];
        float ss = v * v;
        #pragma unroll
        for (int off = 32; off; off >>= 1) ss += __shfl_xor(ss, off, 64);
        const float inv = 1.0f / fmaxf(sqrtf(ss), 1e-12f);
        const float en = v * inv;
        e_norm[n * EDIM + lane] = en;
        // swizzled fp16 write (c = lane)
        const int grp = n >> 6, cs = n & 63;
        const int sub = cs >> 4, colb = cs & 15;
        const int o = lane >> 3, j = lane & 7;     // o: khalf=o>>2, quad=o&3
        const int slot = ((o & 3) * 16 + colb) * 8 + j;
        esw[grp * 4096 + (sub * 2 + (o >> 2)) * 512 + slot] = f2h_bits(en);
        float s2 = en * en;
        #pragma unroll
        for (int off = 32; off; off >>= 1) s2 += __shfl_xor(s2, off, 64);
        if (lane == 0) se_half[n] = 0.5f * s2;
    } else {
        // --- pixels: single-pass normalize -> zn fp32 row-major [p][c] ---
        const int p = (blockIdx.x - NE / 4) * 256 + threadIdx.x;
        const int b = p >> 12, hw = p & (HW - 1);
        const float* zp = z + b * (EDIM * HW) + hw;
        float v[EDIM];
        #pragma unroll
        for (int c = 0; c < EDIM; ++c) v[c] = zp[c * HW];
        float ss = 0.0f;
        #pragma unroll
        for (int c = 0; c < EDIM; ++c) ss = fmaf(v[c], v[c], ss);
        const float inv = 1.0f / fmaxf(sqrtf(ss), 1e-12f);
        #pragma unroll
        for (int c4 = 0; c4 < 16; ++c4) {
            float4 o;
            o.x = v[c4 * 4 + 0] * inv;
            o.y = v[c4 * 4 + 1] * inv;
            o.z = v[c4 * 4 + 2] * inv;
            o.w = v[c4 * 4 + 3] * inv;
            *(float4*)(zn + p * EDIM + c4 * 4) = o;
        }
    }
}

// ---------------- tier-1 k_mfma: split-K partial top-2, 16-wave blocks ------
// Block: 16 waves x 32 pixels = 512 pixels, one codebook quarter (blockIdx.y).
// v = dot + 2 in [1,3]; argmin dist == argmax v (unit vectors). Low 7 mantissa
// bits carry the candidate id (stage*8+sub, 16 stages). Layouts (HW-verified):
// A[m=lane&15][k=quad*8+j], B[k=quad*8+j][n=lane&15], C/D row=(lane>>4)*4+reg,
// col=lane&15.
__global__ __launch_bounds__(1024, 1) void k_mfma(const float* __restrict__ zn,
                                                  const short* __restrict__ esw,
                                                  float2* __restrict__ pv,   // [g][p] {b1,b2} (max-space)
                                                  unsigned* __restrict__ pi) // [g][p] i1
{
    __shared__ __align__(16) short es[2][NSTAGE * EDIM];   // 2 x 16KB

    const int tid  = threadIdx.x;             // 0..1023
    const int wave = tid >> 6, lane = tid & 63;
    const int quad = lane >> 4, col = lane & 15;
    const int p0   = blockIdx.x * 512 + wave * 32;  // wave's 32 pixels (2 sets)
    const int g    = blockIdx.y;                    // codebook quarter
    const int kbase = g * CPS;

    // A fragments: 2 sets of 16 pixels; fp32 zn -> fp16 (single product)
    f16x8 ah[NSET][2];
    #pragma unroll
    for (int s = 0; s < NSET; ++s) {
        const float* zr = zn + (p0 + s * 16 + col) * EDIM;
        #pragma unroll
        for (int kc = 0; kc < 2; ++kc) {
            float f[8];
            *(float4*)(f + 0) = *(const float4*)(zr + kc * 32 + quad * 8 + 0);
            *(float4*)(f + 4) = *(const float4*)(zr + kc * 32 + quad * 8 + 4);
            #pragma unroll
            for (int i = 0; i < 8; ++i) ah[s][kc][i] = (_Float16)f[i];
        }
    }

    // top-2 state in max-space; values stuffed with 7-bit id; b1 >= b2 invariant
    float b1[NSET][4], b2[NSET][4];
    #pragma unroll
    for (int s = 0; s < NSET; ++s)
        #pragma unroll
        for (int r = 0; r < 4; ++r) { b1[s][r] = 0.0f; b2[s][r] = 0.0f; }

    const f32x4 cini = {2.0f, 2.0f, 2.0f, 2.0f};   // |z|=|e|=1 -> bias constant

    // staging: 16 combos x 1KB per 16KB stage, 1 combo per wave (16 waves)
    const int combo0 = wave;
    const char* gsrc0 = (const char*)esw + (size_t)kbase * 128
                        + combo0 * 1024 + lane * 16;
    // prologue: issue stage 0 -> buf 0
    gload_lds16(gsrc0, (char*)&es[0][0] + combo0 * 1024);

    for (int nb = 0; nb < NSTG; ++nb) {
        const int cur = nb & 1;
        __syncthreads();   // vmcnt drained: buf[cur] complete; buf[cur^1] reusable
        if (nb + 1 < NSTG) {
            const char* gsrc = gsrc0 + (size_t)(nb + 1) * (NSTAGE * EDIM * 2);
            gload_lds16(gsrc, (char*)&es[cur ^ 1][0] + combo0 * 1024);
        }

        const short* esb = es[cur];
        #pragma unroll
        for (int sub = 0; sub < 8; ++sub) {       // 8 subtiles of 16 codes
            const short* base = esb + sub * 1024;
            const f16x8 bh0 = *(const f16x8*)(base + lane * 8);
            const f16x8 bh1 = *(const f16x8*)(base + 512 + lane * 8);
            const unsigned sid = (unsigned)((nb << 3) | sub);  // 7-bit id, uniform
            #pragma unroll
            for (int s = 0; s < NSET; ++s) {
                // 2-deep chain seeded with C = {2.0}
                f32x4 acc;
                acc = __builtin_amdgcn_mfma_f32_16x16x32_f16(ah[s][0], bh0, cini, 0, 0, 0);
                acc = __builtin_amdgcn_mfma_f32_16x16x32_f16(ah[s][1], bh1, acc, 0, 0, 0);
                #pragma unroll
                for (int r = 0; r < 4; ++r) {
                    // stuff candidate id into low mantissa bits (v_and_or_b32)
                    const float v = __uint_as_float(
                        (__float_as_uint(acc[r]) & 0xFFFFFF80u) | sid);
                    // b1>=b2 invariant -> med3 == new 2nd-max; then running max
                    b2[s][r] = __builtin_amdgcn_fmed3f(v, b2[s][r], b1[s][r]);
                    b1[s][r] = fmaxf(b1[s][r], v);
                }
            }
        }
    }

    // recover winning index from b1's stuffed id (col is lane-implicit)
    int i1[NSET][4];
    #pragma unroll
    for (int s = 0; s < NSET; ++s)
        #pragma unroll
        for (int r = 0; r < 4; ++r) {
            const unsigned id7 = __float_as_uint(b1[s][r]) & 127u;
            i1[s][r] = kbase + (int)(id7 << 4) + col;
        }

    // merge top-2 across the 16 col-lanes (xor 1,2,4,8 stays inside quad group)
    #pragma unroll
    for (int m = 1; m <= 8; m <<= 1) {
        #pragma unroll
        for (int s = 0; s < NSET; ++s)
            #pragma unroll
            for (int r = 0; r < 4; ++r) {
                const float ob1 = __shfl_xor(b1[s][r], m, 64);
                const int   oi1 = __shfl_xor(i1[s][r], m, 64);
                const float ob2 = __shfl_xor(b2[s][r], m, 64);
                const bool take = (ob1 > b1[s][r]) || (ob1 == b1[s][r] && oi1 < i1[s][r]);
                b2[s][r] = fmaxf(fmaxf(b2[s][r], ob2), fminf(b1[s][r], ob1));
                b1[s][r] = take ? ob1 : b1[s][r];
                i1[s][r] = take ? oi1 : i1[s][r];
            }
    }
    if (col == 0) {
        #pragma unroll
        for (int s = 0; s < NSET; ++s)
            #pragma unroll
            for (int r = 0; r < 4; ++r) {
                const int p = p0 + s * 16 + quad * 4 + r;   // C/D row = quad*4 + r
                pv[g * NPIX + p] = make_float2(b1[s][r], b2[s][r]);
                pi[g * NPIX + p] = (unsigned)i1[s][r];
            }
    }
}

// ---------------- merge: combine splits; rescore shortlist; enqueue suspects -
// thr = gb1 - MARGIN1. gb2 < thr -> unflagged fast path (gi1). Else: exact
// fp32 rescore of the shortlist {i1[g] : b1[g] >= thr}. If no split's
// b2 >= thr the shortlist is complete -> final. Else seed packed[p] with the
// shortlist key and enqueue 4 (pixel, 512-chunk) entries per suspect split
// (b2 >= thr); k_recheck atomicMins the exact scan of those chunks.
__global__ __launch_bounds__(256) void k_merge(const float2* __restrict__ pv,
                                               const unsigned* __restrict__ pi,
                                               const float* __restrict__ zn,
                                               const float* __restrict__ e_norm,
                                               const float* __restrict__ se_half,
                                               unsigned* __restrict__ idx_arr,
                                               unsigned* __restrict__ list2,
                                               unsigned* __restrict__ counter,
                                               unsigned long long* __restrict__ packed) {
    const int p = blockIdx.x * 256 + threadIdx.x;
    float2 v[KSPLIT]; unsigned ix[KSPLIT];
    #pragma unroll
    for (int gg = 0; gg < KSPLIT; ++gg) {
        v[gg] = pv[gg * NPIX + p];
        ix[gg] = pi[gg * NPIX + p];
    }
    // global noisy top-1 (ascending g + strict > == first-occurrence)
    float gb1 = v[0].x; unsigned gi1 = ix[0]; int win = 0;
    #pragma unroll
    for (int gg = 1; gg < KSPLIT; ++gg)
        if (v[gg].x > gb1) { gb1 = v[gg].x; gi1 = ix[gg]; win = gg; }
    float gb2 = -3.0e38f;
    #pragma unroll
    for (int gg = 0; gg < KSPLIT; ++gg) {
        gb2 = fmaxf(gb2, v[gg].y);
        if (gg != win) gb2 = fmaxf(gb2, v[gg].x);
    }
    const float thr = gb1 - MARGIN1;
    if (gb2 < thr) {                      // clear winner
        idx_arr[p] = gi1;
        return;
    }
    // exact fp32 rescore of the shortlist {i1[g] : b1[g] >= thr}
    float zr[EDIM];
    #pragma unroll
    for (int c4 = 0; c4 < 16; ++c4)
        *(float4*)(zr + c4 * 4) = *(const float4*)(zn + (size_t)p * EDIM + c4 * 4);
    float best = 3.0e38f; int bidx = 0x7FFFFFFF;
    #pragma unroll
    for (int gg = 0; gg < KSPLIT; ++gg) {
        if (v[gg].x >= thr) {
            const int c = (int)ix[gg];
            const float* er = e_norm + (size_t)c * EDIM;
            float s = 0.0f;
            #pragma unroll
            for (int k = 0; k < EDIM; ++k) s = fmaf(zr[k], er[k], s);
            const float d = se_half[c] - s;
            if (d < best || (d == best && c < bidx)) { best = d; bidx = c; }
        }
    }
    bool esc = false;
    #pragma unroll
    for (int gg = 0; gg < KSPLIT; ++gg) esc |= (v[gg].y >= thr);
    if (!esc) {                           // shortlist provably complete
        idx_arr[p] = (unsigned)bidx;
        return;
    }
    // escalate: seed with shortlist key; scan only suspect splits' chunks
    packed[p] = ((unsigned long long)order_u32(best) << 32) | (unsigned)bidx;
    idx_arr[p] = 0x80000000u | (unsigned)bidx;
    #pragma unroll
    for (int gg = 0; gg < KSPLIT; ++gg) {
        if (v[gg].y >= thr) {
            const unsigned pos = atomicAdd(&counter[0], 4u);
            if (pos + 3 < 2 * NPIX) {
                list2[pos]     = (unsigned)p | ((unsigned)(gg * 4)     << 16);
                list2[pos + 1] = (unsigned)p | ((unsigned)(gg * 4 + 1) << 16);
                list2[pos + 2] = (unsigned)p | ((unsigned)(gg * 4 + 2) << 16);
                list2[pos + 3] = (unsigned)p | ((unsigned)(gg * 4 + 3) << 16);
            }
        }
    }
}

// ---------------- tier-3: exact fp32 scan of suspect (pixel, chunk) items ----
// entry = p | (chunk << 16); chunk = 512-code block. Coalesced: 4 codes x 16
// lanes per b128 (contiguous 1KB from L2-resident e_norm); 4 independent
// shfl-reduce chains. One wave per entry, grid-strided.
__global__ __launch_bounds__(256) void k_recheck(const float* __restrict__ zn,
                                                 const float* __restrict__ e_norm,
                                                 const float* __restrict__ se_half,
                                                 const unsigned* __restrict__ list2,
                                                 const unsigned* __restrict__ counter,
                                                 unsigned long long* __restrict__ packed) {
    const int lane  = threadIdx.x & 63;
    const int k     = lane >> 4;        // code-in-group 0..3
    const int m     = lane & 15;        // c4 index 0..15
    const int wglob = (blockIdx.x * 256 + threadIdx.x) >> 6;
    const int nwav  = (gridDim.x * 256) >> 6;
    int cnt = (int)counter[0]; if (cnt > 2 * NPIX) cnt = 2 * NPIX;
    const float4* e4 = (const float4*)e_norm;

    for (int item = wglob; item < cnt; item += nwav) {
        const unsigned e = list2[item];
        const int p     = (int)(e & 0xFFFFu);
        const int chunk = (int)(e >> 16);
        const float4 zv = *(const float4*)(zn + (size_t)p * EDIM + m * 4);
        float best = 3.0e38f; int bidx = 0;
        for (int t4 = 0; t4 < 32; ++t4) {              // 16 codes per iteration
            float s[4]; int n[4];
            #pragma unroll
            for (int j = 0; j < 4; ++j) {
                n[j] = chunk * 512 + (t4 * 4 + j) * 4 + k;
                const float4 ev = e4[n[j] * 16 + m];   // lane-linear: 1KB contiguous
                s[j] = fmaf(zv.w, ev.w, fmaf(zv.z, ev.z,
                       fmaf(zv.y, ev.y, zv.x * ev.x)));
            }
            #pragma unroll
            for (int j = 0; j < 4; ++j) s[j] += __shfl_xor(s[j], 1, 64);
            #pragma unroll
            for (int j = 0; j < 4; ++j) s[j] += __shfl_xor(s[j], 2, 64);
            #pragma unroll
            for (int j = 0; j < 4; ++j) s[j] += __shfl_xor(s[j], 4, 64);
            #pragma unroll
            for (int j = 0; j < 4; ++j) s[j] += __shfl_xor(s[j], 8, 64);
            #pragma unroll
            for (int j = 0; j < 4; ++j) {              // codes ascend over (t4,j)
                const float d = se_half[n[j]] - s[j];
                if (d < best) { best = d; bidx = n[j]; }
            }
        }
        #pragma unroll
        for (int mm = 1; mm <= 32; mm <<= 1) {         // wave first-min
            const float ob = __shfl_xor(best, mm, 64);
            const int   oi = __shfl_xor(bidx, mm, 64);
            if (ob < best || (ob == best && oi < bidx)) { best = ob; bidx = oi; }
        }
        if (lane == 0) {
            const unsigned long long key =
                ((unsigned long long)order_u32(best) << 32) | (unsigned)bidx;
            atomicMin(&packed[p], key);
        }
    }
}

// ---------------- finalize: write indices + gather z_q (4 thr/pixel) ---------
__global__ __launch_bounds__(256) void k_finalize(const unsigned* __restrict__ idx_arr,
                                                  const unsigned long long* __restrict__ packed,
                                                  const float* __restrict__ e_norm,
                                                  float* __restrict__ out) {
    const int pl = threadIdx.x & 63;
    const int q  = threadIdx.x >> 6;                  // channel quarter 0..3
    const int p  = blockIdx.x * 64 + pl;
    const unsigned v = idx_arr[p];
    const int bidx = (v & 0x80000000u) ? (int)(packed[p] & 0xFFFFFFFFull)
                                       : (int)v;
    if (q == 0) out[NPIX * EDIM + p] = (float)bidx;
    const int b = p >> 12, hw = p & (HW - 1);
    float* op = out + b * (EDIM * HW) + hw;
    const float4* ep4 = (const float4*)(e_norm + (size_t)bidx * EDIM + q * 16);
    #pragma unroll
    for (int j = 0; j < 4; ++j) {
        const float4 e = ep4[j];
        const int c = q * 16 + j * 4;
        op[(c + 0) * HW] = e.x; op[(c + 1) * HW] = e.y;   // coalesced per c
        op[(c + 2) * HW] = e.z; op[(c + 3) * HW] = e.w;
    }
}

extern "C" void kernel_launch(void* const* d_in, const int* in_sizes, int n_in,
                              void* d_out, int out_size, void* d_ws, size_t ws_size,
                              hipStream_t stream) {
    const float* z   = (const float*)d_in[0];
    const float* emb = (const float*)d_in[1];
    float* out = (float*)d_out;

    // workspace layout (~13.8 MB)
    float* e_norm  = (float*)d_ws;                       // 2 MB
    float* se_half = e_norm + NE * EDIM;                 // 32 KB
    short* esw = (short*)(se_half + NE);                 // 1 MB (swizzled fp16)
    float* zn = (float*)(esw + NE * EDIM);               // 8 MB
    unsigned* idx_arr = (unsigned*)(zn + NPIX * EDIM);   // 128 KB
    unsigned* list2   = idx_arr + NPIX;                  // 256 KB (suspect items)
    unsigned* counter = list2 + 2 * NPIX;                // 4 B (+pad)
    unsigned long long* packed = (unsigned long long*)(counter + 64); // 256 KB
    float2*   pv = (float2*)(packed + NPIX);             // 1 MB
    unsigned* pi = (unsigned*)(pv + KSPLIT * NPIX);      // 512 KB

    k_prep<<<NE / 4 + NPIX / 256, 256, 0, stream>>>(emb, z, e_norm, se_half,
                                                    esw, zn, counter);
    k_mfma<<<dim3(NPIX / 512, KSPLIT), 1024, 0, stream>>>(zn, esw, pv, pi);
    k_merge<<<NPIX / 256, 256, 0, stream>>>(pv, pi, zn, e_norm, se_half,
                                            idx_arr, list2, counter, packed);
    k_recheck<<<1024, 256, 0, stream>>>(zn, e_norm, se_half, list2, counter, packed);
    k_finalize<<<NPIX / 64, 256, 0, stream>>>(idx_arr, packed, e_norm, out);
}